// Round 11
// baseline (33.494 us; speedup 1.0000x reference)
//
#include <hip/hip_runtime.h>
#include <math.h>

// DifferentiableLogicLayer:
//   out[b,g] = c0[g] + ca[g]*a + cb[g]*b + cab[g]*a*b   (affine collapse of
//   the 16 soft-logic ops dotted with softmax(gate_logits[g]))
//   a = clip(x[b, g%8192]), b = clip(x[b, (g+1)%8192])
//
// R10 lesson: nt-store neutral; fills hit 6.6 TB/s at 8% occupancy/4% VALU
// => HBM saturation needs almost nothing; our remaining k2 gap must be
// per-wave-iteration overhead (loop + shfl/lgkm wait + divergent lane-63
// branch per 1 KB). R11: 32 B per thread (2x dwordx4, 8 gates), halving all
// per-byte overheads and doubling contiguous bytes per wave access.
// k1 (dedup'd softmax table) unchanged.

constexpr int INPUT_SIZE = 8192;
constexpr int NUM_GATES  = 8192;
constexpr int BATCH      = 2048;
constexpr int V8_PER_ROW = INPUT_SIZE / 8;   // 1024 32B-slots per row
constexpr int NBLOCKS    = 2048;             // 524288 threads
constexpr int ROW_STRIDE = 512;              // 524288 / 1024 slots
constexpr int NITER      = BATCH / ROW_STRIDE; // 4 rows per thread

typedef float floatx4 __attribute__((ext_vector_type(4)));

// ---------------------------------------------------------------------------
// Kernel 1: fold softmax(gate_logits) into 4 affine coefficients per gate.
// ---------------------------------------------------------------------------
__global__ __launch_bounds__(256) void gate_weights_kernel(
    const float* __restrict__ logits, floatx4* __restrict__ w) {
    int g = blockIdx.x * blockDim.x + threadIdx.x;
    if (g >= NUM_GATES) return;

    const floatx4* lp = reinterpret_cast<const floatx4*>(logits + (size_t)g * 16);
    floatx4 l0 = lp[0], l1 = lp[1], l2 = lp[2], l3 = lp[3];
    float p[16];
    p[0]=l0.x;  p[1]=l0.y;  p[2]=l0.z;  p[3]=l0.w;
    p[4]=l1.x;  p[5]=l1.y;  p[6]=l1.z;  p[7]=l1.w;
    p[8]=l2.x;  p[9]=l2.y;  p[10]=l2.z; p[11]=l2.w;
    p[12]=l3.x; p[13]=l3.y; p[14]=l3.z; p[15]=l3.w;

    float m = p[0];
    #pragma unroll
    for (int i = 1; i < 16; ++i) m = fmaxf(m, p[i]);
    float s = 0.f;
    #pragma unroll
    for (int i = 0; i < 16; ++i) { p[i] = __expf(p[i] - m); s += p[i]; }
    float inv = 1.f / s;

    float c0  = p[8]+p[9]+p[10]+p[11]+p[12]+p[13]+p[14]+p[15];
    float ca  = p[2]+p[3]+p[6]+p[7] - p[8]-p[9]-p[12]-p[13];
    float cb  = p[4]+p[5]+p[6]+p[7] - p[8]-p[9]-p[10]-p[11];
    float cab = p[1]-p[2]-p[4]-2.f*p[6]-p[7]+p[8]+2.f*p[9]+p[11]+p[13]-p[14];
    floatx4 wv = { c0*inv, ca*inv, cb*inv, cab*inv };
    w[g] = wv;
}

// ---------------------------------------------------------------------------
// Kernel 2: streaming kernel, 32 B (8 gates) per thread per row.
// Per wave-row: 2x contiguous 2KB vector reads, 1 shfl, 1 predicated lane-63
// scalar load, 2x contiguous 2KB stores. 4 row-iterations per thread.
// ---------------------------------------------------------------------------
__global__ __launch_bounds__(256) void dll_main_kernel(
    const float* __restrict__ x,
    const floatx4* __restrict__ w,
    float* __restrict__ out) {

    int tid  = blockIdx.x * blockDim.x + threadIdx.x;   // 0 .. 524287
    int col8 = tid & (V8_PER_ROW - 1);                  // fixed 32B slot
    int row0 = tid >> 10;                               // 0 .. 511
    int lane = threadIdx.x & 63;

    int g  = col8 * 8;
    int gn = (g + 8) & (INPUT_SIZE - 1);                // wrap neighbor index

    // 8 gate-weight vectors (128 B contiguous, L2-resident table)
    floatx4 wv[8];
    #pragma unroll
    for (int i = 0; i < 8; ++i) wv[i] = w[g + i];

    for (int it = 0; it < NITER; ++it) {
        int row = row0 + it * ROW_STRIDE;
        const float* xr = x + (size_t)row * INPUT_SIZE;

        floatx4 x0 = *reinterpret_cast<const floatx4*>(xr + g);
        floatx4 x1 = *reinterpret_cast<const floatx4*>(xr + g + 4);

        // neighbor x[row, g+8] == next lane's x0.x (except lane 63)
        float nb = __shfl_down(x0.x, 1);
        if (lane == 63) nb = xr[gn];

        float a[9];
        a[0] = fminf(fmaxf(x0.x, 0.f), 1.f);
        a[1] = fminf(fmaxf(x0.y, 0.f), 1.f);
        a[2] = fminf(fmaxf(x0.z, 0.f), 1.f);
        a[3] = fminf(fmaxf(x0.w, 0.f), 1.f);
        a[4] = fminf(fmaxf(x1.x, 0.f), 1.f);
        a[5] = fminf(fmaxf(x1.y, 0.f), 1.f);
        a[6] = fminf(fmaxf(x1.z, 0.f), 1.f);
        a[7] = fminf(fmaxf(x1.w, 0.f), 1.f);
        a[8] = fminf(fmaxf(nb,   0.f), 1.f);

        floatx4 o0, o1;
        o0.x = fmaf(wv[0].w, a[0]*a[1], fmaf(wv[0].z, a[1], fmaf(wv[0].y, a[0], wv[0].x)));
        o0.y = fmaf(wv[1].w, a[1]*a[2], fmaf(wv[1].z, a[2], fmaf(wv[1].y, a[1], wv[1].x)));
        o0.z = fmaf(wv[2].w, a[2]*a[3], fmaf(wv[2].z, a[3], fmaf(wv[2].y, a[2], wv[2].x)));
        o0.w = fmaf(wv[3].w, a[3]*a[4], fmaf(wv[3].z, a[4], fmaf(wv[3].y, a[3], wv[3].x)));
        o1.x = fmaf(wv[4].w, a[4]*a[5], fmaf(wv[4].z, a[5], fmaf(wv[4].y, a[4], wv[4].x)));
        o1.y = fmaf(wv[5].w, a[5]*a[6], fmaf(wv[5].z, a[6], fmaf(wv[5].y, a[5], wv[5].x)));
        o1.z = fmaf(wv[6].w, a[6]*a[7], fmaf(wv[6].z, a[7], fmaf(wv[6].y, a[6], wv[6].x)));
        o1.w = fmaf(wv[7].w, a[7]*a[8], fmaf(wv[7].z, a[8], fmaf(wv[7].y, a[7], wv[7].x)));

        float* orow = out + (size_t)row * INPUT_SIZE + g;
        *reinterpret_cast<floatx4*>(orow)     = o0;
        *reinterpret_cast<floatx4*>(orow + 4) = o1;
    }
}

extern "C" void kernel_launch(void* const* d_in, const int* in_sizes, int n_in,
                              void* d_out, int out_size, void* d_ws, size_t ws_size,
                              hipStream_t stream) {
    const float* x      = reinterpret_cast<const float*>(d_in[0]);
    const float* logits = reinterpret_cast<const float*>(d_in[1]);
    float*       out    = reinterpret_cast<float*>(d_out);
    floatx4*     w      = reinterpret_cast<floatx4*>(d_ws);   // 128 KB table

    gate_weights_kernel<<<NUM_GATES / 256, 256, 0, stream>>>(logits, w);
    dll_main_kernel<<<NBLOCKS, 256, 0, stream>>>(x, w, out);
}

// Round 12
// 26.996 us; speedup vs baseline: 1.2407x; 1.2407x over previous
//
#include <hip/hip_runtime.h>
#include <math.h>

// DifferentiableLogicLayer:
//   out[b,g] = c0[g] + ca[g]*a + cb[g]*b + cab[g]*a*b   (affine collapse of
//   the 16 soft-logic ops dotted with softmax(gate_logits[g]))
//   a = clip(x[b, g%8192]), b = clip(x[b, (g+1)%8192])
//
// R11 lesson: 32B/thread tiles break wave coalescing (strided dwordx4) —
// reverted to R10's unit-stride 16B/thread stream.
// R12: kill the k1 dispatch + gap (~4us) WITHOUT R6's fused penalty.
// Column-major blocking: each block owns 64 col4-slots x (all rows / 64
// row-blocks), so its 256 threads need exactly 256 gates => ONE softmax per
// thread (1/4 of R6's redundancy), shared via 4KB LDS. Stream loop is
// byte-identical to R10. Row-0 loads issued BEFORE the prologue so softmax
// hides under HBM latency.

constexpr int INPUT_SIZE = 8192;
constexpr int BATCH      = 2048;
constexpr int V4_PER_ROW = INPUT_SIZE / 4;   // 2048 col4 slots per row
constexpr int NBLOCKS    = 2048;             // 32 colblocks x 64 rowblocks
constexpr int NITER      = 8;                // rows per thread (stride 256)

typedef float floatx4 __attribute__((ext_vector_type(4)));

__device__ __forceinline__ floatx4 softmax_affine(const float* __restrict__ logits, int g) {
    const floatx4* lp = reinterpret_cast<const floatx4*>(logits + (size_t)g * 16);
    floatx4 l0 = lp[0], l1 = lp[1], l2 = lp[2], l3 = lp[3];
    float p[16];
    p[0]=l0.x;  p[1]=l0.y;  p[2]=l0.z;  p[3]=l0.w;
    p[4]=l1.x;  p[5]=l1.y;  p[6]=l1.z;  p[7]=l1.w;
    p[8]=l2.x;  p[9]=l2.y;  p[10]=l2.z; p[11]=l2.w;
    p[12]=l3.x; p[13]=l3.y; p[14]=l3.z; p[15]=l3.w;

    float m = p[0];
    #pragma unroll
    for (int i = 1; i < 16; ++i) m = fmaxf(m, p[i]);
    float s = 0.f;
    #pragma unroll
    for (int i = 0; i < 16; ++i) { p[i] = __expf(p[i] - m); s += p[i]; }
    float inv = 1.f / s;

    float c0  = p[8]+p[9]+p[10]+p[11]+p[12]+p[13]+p[14]+p[15];
    float ca  = p[2]+p[3]+p[6]+p[7] - p[8]-p[9]-p[12]-p[13];
    float cb  = p[4]+p[5]+p[6]+p[7] - p[8]-p[9]-p[10]-p[11];
    float cab = p[1]-p[2]-p[4]-2.f*p[6]-p[7]+p[8]+2.f*p[9]+p[11]+p[13]-p[14];
    floatx4 wv = { c0*inv, ca*inv, cb*inv, cab*inv };
    return wv;
}

__global__ __launch_bounds__(256) void dll_fused_colmajor(
    const float* __restrict__ x,
    const float* __restrict__ logits,
    float* __restrict__ out) {

    __shared__ floatx4 wlds[256];            // this block's 256 gate weights

    int colblock = blockIdx.x & 31;          // 32 column blocks
    int rowblock = blockIdx.x >> 5;          // 64 row blocks
    int c_local  = threadIdx.x & 63;         // lane == column within wave
    int rslot    = threadIdx.x >> 6;         // 4 row-slots per block

    int col4 = colblock * 64 + c_local;      // fixed col4 slot (wave: unit-stride)
    int g    = col4 * 4;
    int gn   = (g + 4) & (INPUT_SIZE - 1);   // wrap neighbor index
    int row0 = rowblock * 4 + rslot;         // 0 .. 255

    // ---- prefetch row-0's loads BEFORE the prologue (hides softmax) ------
    const float* xr0 = x + (size_t)row0 * INPUT_SIZE;
    floatx4 xv_c = *reinterpret_cast<const floatx4*>(xr0 + g);
    float   nb_raw = xr0[gn];                // only lane 63's value is used

    // ---- prologue: ONE softmax per thread, shared via LDS ----------------
    wlds[threadIdx.x] = softmax_affine(logits, colblock * 256 + threadIdx.x);
    __syncthreads();

    floatx4 w0 = wlds[c_local * 4 + 0];
    floatx4 w1 = wlds[c_local * 4 + 1];
    floatx4 w2 = wlds[c_local * 4 + 2];
    floatx4 w3 = wlds[c_local * 4 + 3];

    // ---- stream loop: byte-identical access pattern to R10 ---------------
    #pragma unroll
    for (int it = 0; it < NITER; ++it) {
        int row = row0 + it * 256;

        float nb = __shfl_down(xv_c.x, 1);
        if (c_local == 63) nb = nb_raw;

        float a0 = fminf(fmaxf(xv_c.x, 0.f), 1.f);
        float a1 = fminf(fmaxf(xv_c.y, 0.f), 1.f);
        float a2 = fminf(fmaxf(xv_c.z, 0.f), 1.f);
        float a3 = fminf(fmaxf(xv_c.w, 0.f), 1.f);
        float a4 = fminf(fmaxf(nb,     0.f), 1.f);

        floatx4 o;
        o.x = fmaf(w0.w, a0 * a1, fmaf(w0.z, a1, fmaf(w0.y, a0, w0.x)));
        o.y = fmaf(w1.w, a1 * a2, fmaf(w1.z, a2, fmaf(w1.y, a1, w1.x)));
        o.z = fmaf(w2.w, a2 * a3, fmaf(w2.z, a3, fmaf(w2.y, a2, w2.x)));
        o.w = fmaf(w3.w, a3 * a4, fmaf(w3.z, a4, fmaf(w3.y, a3, w3.x)));

        // prefetch next iteration before the store (compiler pipelines)
        if (it + 1 < NITER) {
            const float* xr = x + (size_t)(row + 256) * INPUT_SIZE;
            xv_c   = *reinterpret_cast<const floatx4*>(xr + g);
            nb_raw = xr[gn];
        }

        *reinterpret_cast<floatx4*>(out + (size_t)row * INPUT_SIZE + g) = o;
    }
}

extern "C" void kernel_launch(void* const* d_in, const int* in_sizes, int n_in,
                              void* d_out, int out_size, void* d_ws, size_t ws_size,
                              hipStream_t stream) {
    const float* x      = reinterpret_cast<const float*>(d_in[0]);
    const float* logits = reinterpret_cast<const float*>(d_in[1]);
    float*       out    = reinterpret_cast<float*>(d_out);

    dll_fused_colmajor<<<NBLOCKS, 256, 0, stream>>>(x, logits, out);
}